// Round 8
// baseline (2305.088 us; speedup 1.0000x reference)
//
#include <hip/hip_runtime.h>
#include <cmath>

#define S_CNT 50
#define T_CNT 2048
#define I_DIM 64
#define H_DIM 256

typedef float vf2 __attribute__((ext_vector_type(2)));

__device__ __forceinline__ float fast_tanh(float x) {
    float e = __expf(2.0f * x);
    return 1.0f - __fdividef(2.0f, e + 1.0f);
}

__device__ __forceinline__ vf2 pkfma(vf2 a, vf2 b, vf2 c) {
#if __has_builtin(__builtin_elementwise_fma)
    return __builtin_elementwise_fma(a, b, c);
#else
    vf2 r; r.x = fmaf(a.x, b.x, c.x); r.y = fmaf(a.y, b.y, c.y); return r;
#endif
}

__device__ __forceinline__ float fma4(const float4 w, const float4 h, float a) {
    a = fmaf(w.x, h.x, a);
    a = fmaf(w.y, h.y, a);
    a = fmaf(w.z, h.z, a);
    a = fmaf(w.w, h.w, a);
    return a;
}

// x + DPP(x): VALU-pipe cross-lane add. CTRLs: 0xB1 quad xor1, 0x4E quad xor2,
// 0x141 row_half_mirror (xor7 within 16), 0x140 row_mirror (xor15 within 16).
template <int CTRL>
__device__ __forceinline__ float dpp_xadd(float x) {
    const int xi = __float_as_int(x);
    const int yi = __builtin_amdgcn_update_dpp(xi, xi, CTRL, 0xF, 0xF, false);
    return x + __int_as_float(yi);
}

// Workgroup barrier that drains ONLY LDS (lgkmcnt), leaving global loads and
// stores (vmcnt) in flight across the barrier. __syncthreads() would emit
// s_waitcnt vmcnt(0) and serialize the per-step global h-store / u-prefetch.
__device__ __forceinline__ void lgkm_barrier() {
    asm volatile("s_waitcnt lgkmcnt(0)\n\ts_barrier" ::: "memory");
}

// U[s][t][j] = b_ih[s][j] + b_hh[s][j] + W_ih[s][j]·x[s][t]
// 128 threads, 2 rows/thread (j, j+128) -> halves LDS broadcast instrs.
__launch_bounds__(128, 8)
__global__ void precompute_u2(const float* __restrict__ input_data,
                              const float* __restrict__ W_ih,
                              const float* __restrict__ b_ih,
                              const float* __restrict__ b_hh,
                              float* __restrict__ U)
{
    const int s  = blockIdx.x;
    const int tb = blockIdx.y;   // 16 t-slices of 128 steps
    const int j  = threadIdx.x;  // rows j and j+128

    vf2 wa[32], wb[32];
    {
        const float4* ra = reinterpret_cast<const float4*>(
            W_ih + ((size_t)s * H_DIM + j) * I_DIM);
        const float4* rb = reinterpret_cast<const float4*>(
            W_ih + ((size_t)s * H_DIM + j + 128) * I_DIM);
#pragma unroll
        for (int k = 0; k < 16; ++k) {
            const float4 va = ra[k], vb = rb[k];
            wa[2 * k]     = vf2{va.x, va.y};
            wa[2 * k + 1] = vf2{va.z, va.w};
            wb[2 * k]     = vf2{vb.x, vb.y};
            wb[2 * k + 1] = vf2{vb.z, vb.w};
        }
    }
    const float ba = b_ih[s * H_DIM + j] + b_hh[s * H_DIM + j];
    const float bb = b_ih[s * H_DIM + j + 128] + b_hh[s * H_DIM + j + 128];

    __shared__ float xs[32][I_DIM];
    const float* inb = input_data + (size_t)s * T_CNT * 65;
    float* Ub = U + (size_t)s * T_CNT * H_DIM;

    for (int c = 0; c < 4; ++c) {
        const int t0 = tb * 128 + c * 32;
        __syncthreads();
        for (int idx = j; idx < 32 * I_DIM; idx += 128) {
            const int row = idx >> 6, col = idx & 63;
            xs[row][col] = inb[(size_t)(t0 + row) * 65 + 1 + col];
        }
        __syncthreads();
        for (int tt = 0; tt < 32; ++tt) {
            const float4* xv = reinterpret_cast<const float4*>(&xs[tt][0]);
            vf2 aa = vf2{0.f, 0.f}, ab = vf2{0.f, 0.f};
            vf2 ca = vf2{0.f, 0.f}, cb = vf2{0.f, 0.f};
#pragma unroll
            for (int k = 0; k < 16; ++k) {
                const float4 x4 = xv[k];
                const vf2 xlo = vf2{x4.x, x4.y};
                const vf2 xhi = vf2{x4.z, x4.w};
                aa = pkfma(wa[2 * k],     xlo, aa);
                ca = pkfma(wa[2 * k + 1], xhi, ca);
                ab = pkfma(wb[2 * k],     xlo, ab);
                cb = pkfma(wb[2 * k + 1], xhi, cb);
            }
            const vf2 sa = aa + ca, sb = ab + cb;
            Ub[(size_t)(t0 + tt) * H_DIM + j]       = ba + sa.x + sa.y;
            Ub[(size_t)(t0 + tt) * H_DIM + j + 128] = bb + sb.x + sb.y;
        }
    }
}

// Main recurrence, 512 threads: tid = g*16 + p. Group g owns rows 8g..8g+7;
// lane p owns float4 col-chunks f = 16m+p (m=0..3) => 16 h floats/lane.
// Per step per wave: 4 ds_read_b128 + 1 ds_write_b32. Reduce of 8 row
// partials over 16 lanes is ALL-DPP: xor1 -> xor7 -> xor15 -> xor2 with
// select bits s1=b0^b2, s2=b0^b3, s3=b3 (row jr = s1|s2<<1|s3<<2; lanes
// p and p^2 duplicate; !(p&2) writes). h_t overwrites the consumed U slot.
__launch_bounds__(512, 2)
__global__ void rnn_main6(const float* __restrict__ hidden,
                          const float* __restrict__ W_hh,
                          float* __restrict__ U)
{
    const int s   = blockIdx.x;
    const int tid = threadIdx.x;
    const int g   = tid >> 4;     // 0..31: rows 8g..8g+7
    const int p   = tid & 15;     // col slice

    const int s1 = ((p ^ (p >> 2)) & 1);
    const int s2 = ((p ^ (p >> 3)) & 1);
    const int s3 = ((p >> 3) & 1);
    const int jr = s1 | (s2 << 1) | (s3 << 2);
    const int jown = 8 * g + jr;
    const bool wr = ((p & 2) == 0);

    __shared__ __align__(16) float hA[H_DIM];
    __shared__ __align__(16) float hB[H_DIM];

    if (tid < H_DIM) hA[tid] = hidden[s * H_DIM + tid];

    // weights: 8 rows x 4 float4 chunks (f = 16m+p) as vf2 pairs = 128 VGPR
    vf2 w2[8][8];
#pragma unroll
    for (int r = 0; r < 8; ++r) {
        const float4* wrow = reinterpret_cast<const float4*>(
            W_hh + ((size_t)s * H_DIM + 8 * g + r) * H_DIM);
#pragma unroll
        for (int m = 0; m < 4; ++m) {
            const float4 wv = wrow[16 * m + p];
            w2[r][2 * m]     = vf2{wv.x, wv.y};
            w2[r][2 * m + 1] = vf2{wv.z, wv.w};
        }
    }

    float* Ub = U + (size_t)s * T_CNT * H_DIM;
    const float* uq = Ub + jown;
    float*       us = Ub + jown;
    float ucur = *uq;
    uq += H_DIM;

    __syncthreads();

#define RNN_STEP(HRD, HWR)                                                    \
    {                                                                         \
        const float unext = *uq;   /* prefetch t+1 (U padded at end) */       \
        uq += H_DIM;                                                          \
        const float4* hv = reinterpret_cast<const float4*>(HRD);              \
        vf2 acc[8];                                                           \
        _Pragma("unroll")                                                     \
        for (int r = 0; r < 8; ++r) acc[r] = vf2{0.f, 0.f};                   \
        _Pragma("unroll")                                                     \
        for (int m = 0; m < 4; ++m) {                                         \
            const float4 h4 = hv[16 * m + p];                                 \
            const vf2 hlo = vf2{h4.x, h4.y};                                  \
            const vf2 hhi = vf2{h4.z, h4.w};                                  \
            _Pragma("unroll")                                                 \
            for (int r = 0; r < 8; ++r) {                                     \
                acc[r] = pkfma(w2[r][2 * m],     hlo, acc[r]);                \
                acc[r] = pkfma(w2[r][2 * m + 1], hhi, acc[r]);                \
            }                                                                 \
        }                                                                     \
        float d[8];                                                           \
        _Pragma("unroll")                                                     \
        for (int r = 0; r < 8; ++r) d[r] = acc[r].x + acc[r].y;               \
        /* stage 1: xor1 (quad DPP), keep row-bit0 = s1 */                    \
        _Pragma("unroll")                                                     \
        for (int r = 0; r < 8; ++r) d[r] = dpp_xadd<0xB1>(d[r]);              \
        float e0 = s1 ? d[1] : d[0];                                          \
        float e1 = s1 ? d[3] : d[2];                                          \
        float e2 = s1 ? d[5] : d[4];                                          \
        float e3 = s1 ? d[7] : d[6];                                          \
        /* stage 2: xor7 (row_half_mirror), keep row-bit1 = s2 */             \
        e0 = dpp_xadd<0x141>(e0);                                             \
        e1 = dpp_xadd<0x141>(e1);                                             \
        e2 = dpp_xadd<0x141>(e2);                                             \
        e3 = dpp_xadd<0x141>(e3);                                             \
        float f0 = s2 ? e1 : e0;                                              \
        float f1 = s2 ? e3 : e2;                                              \
        /* stage 3: xor15 (row_mirror), keep row-bit2 = s3 */                 \
        f0 = dpp_xadd<0x140>(f0);                                             \
        f1 = dpp_xadd<0x140>(f1);                                             \
        float v = s3 ? f1 : f0;                                               \
        /* stage 4: xor2 (quad DPP), duplicate merge */                       \
        v = dpp_xadd<0x4E>(v);                                                \
        const float hval = fast_tanh(v + ucur);                               \
        if (wr) { (HWR)[jown] = hval; *us = hval; }                           \
        us += H_DIM;                                                          \
        ucur = unext;                                                         \
        lgkm_barrier();                                                       \
    }

    for (int t = 0; t < T_CNT; t += 2) {
        RNN_STEP(hA, hB)
        RNN_STEP(hB, hA)
    }
#undef RNN_STEP
}

// finalize: sigma[s][t] = |W_lin·h_t + b_lin|, log-lik reduction.
// H == U buffer (overwritten by rnn_main6 with h_t).
__launch_bounds__(256, 4)
__global__ void finalize_kernel(const float* __restrict__ input_data,
                                const float* __restrict__ fe,
                                const float* __restrict__ W_lin,
                                const float* __restrict__ b_lin,
                                const float* __restrict__ H,
                                float* __restrict__ out)
{
    const int s    = blockIdx.x;
    const int tb   = blockIdx.y;   // 4 slices of 512 timesteps
    const int tid  = threadIdx.x;
    const int wave = tid >> 6;
    const int lane = tid & 63;

    const float4 wl =
        reinterpret_cast<const float4*>(W_lin + s * H_DIM)[lane];
    const float blin = b_lin[s];
    const float* Hb  = H + (size_t)s * T_CNT * H_DIM;
    const float* inb = input_data + (size_t)s * T_CNT * 65;
    const float* feb = fe + (size_t)s * T_CNT;
    float* sig_out   = out + 1 + (size_t)s * T_CNT;

    float ll = 0.f;
    for (int i = 0; i < 128; ++i) {
        const int t = tb * 512 + 4 * i + wave;
        const float4 h4 =
            reinterpret_cast<const float4*>(Hb + (size_t)t * H_DIM)[lane];
        float d = fma4(wl, h4, 0.f);
#pragma unroll
        for (int m = 1; m <= 32; m <<= 1) d += __shfl_xor(d, m);
        const float sigma = fabsf(d + blin);
        if (lane == 0) {
            sig_out[t] = sigma;
            const float diff = inb[(size_t)t * 65] - feb[t];
            ll -= (diff * diff) / (2.f * sigma * sigma);
        }
    }
    __shared__ float red[4];
    if (lane == 0) red[wave] = ll;
    __syncthreads();
    if (tid == 0) atomicAdd(out, (red[0] + red[1]) + (red[2] + red[3]));
}

// ---------------- fallback (no workspace): round-3 style, self-contained ----
__launch_bounds__(1024, 4)
__global__ void rnn_fallback_kernel(const float* __restrict__ input_data,
                                    const float* __restrict__ hidden,
                                    const float* __restrict__ fe,
                                    const float* __restrict__ W_ih,
                                    const float* __restrict__ W_hh,
                                    const float* __restrict__ b_ih,
                                    const float* __restrict__ b_hh,
                                    const float* __restrict__ W_lin,
                                    const float* __restrict__ b_lin,
                                    float* __restrict__ out)
{
    const int s    = blockIdx.x;
    const int tid  = threadIdx.x;
    const int j    = tid >> 2;
    const int q    = tid & 3;
    const int lane = tid & 63;
    const int wv   = tid >> 6;

    __shared__ float hbuf[2][H_DIM];
    __shared__ float zbuf[T_CNT];
    __shared__ float febuf[T_CNT];
    __shared__ float wlin_lds[H_DIM];
    __shared__ float wsum[2][16];
    __shared__ float xbuf[64][I_DIM];

    const float* in_base = input_data + (size_t)s * T_CNT * 65;
    const float* fe_base = fe + (size_t)s * T_CNT;

    for (int t = tid; t < T_CNT; t += 1024) {
        zbuf[t]  = in_base[(size_t)t * 65];
        febuf[t] = fe_base[t];
    }
    if (tid < H_DIM) {
        hbuf[1][tid]  = hidden[s * H_DIM + tid];
        wlin_lds[tid] = W_lin[s * H_DIM + tid];
    }

    float4 w[16];
    {
        const float4* wrow =
            reinterpret_cast<const float4*>(W_hh + ((size_t)s * H_DIM + j) * H_DIM);
#pragma unroll
        for (int m = 0; m < 16; ++m) w[m] = wrow[4 * m + q];
    }
    float4 wx[4];
    {
        const float4* wxrow =
            reinterpret_cast<const float4*>(W_ih + ((size_t)s * H_DIM + j) * I_DIM);
#pragma unroll
        for (int m = 0; m < 4; ++m) wx[m] = wxrow[4 * m + q];
    }
    const float badd = b_ih[s * H_DIM + j] + b_hh[s * H_DIM + j];
    const float blin = b_lin[s];
    float* sig_out = out + 1 + (size_t)s * T_CNT;

    float ll = 0.f, sv_prev = 0.f;
    __syncthreads();

    for (int c = 0; c < T_CNT / 64; ++c) {
        for (int idx = tid; idx < 64 * I_DIM; idx += 1024) {
            const int row = idx >> 6, col = idx & 63;
            xbuf[row][col] = in_base[(size_t)(c * 64 + row) * 65 + 1 + col];
        }
        __syncthreads();
        for (int tt = 0; tt < 64; ++tt) {
            const int t  = c * 64 + tt;
            const int rp = (t + 1) & 1;
            {
                float sv = sv_prev;
                sv += __shfl_xor(sv, 4);
                sv += __shfl_xor(sv, 8);
                sv += __shfl_xor(sv, 16);
                sv += __shfl_xor(sv, 32);
                if (lane == 0) wsum[(t - 1) & 1][wv] = sv;
            }
            if (tid == 0 && t >= 2) {
                const int tm = t - 2;
                const float* wp = wsum[tm & 1];
                float sg = (((wp[0] + wp[1]) + (wp[2] + wp[3])) +
                            ((wp[4] + wp[5]) + (wp[6] + wp[7]))) +
                           (((wp[8] + wp[9]) + (wp[10] + wp[11])) +
                            ((wp[12] + wp[13]) + (wp[14] + wp[15]))) + blin;
                const float sigma = fabsf(sg);
                sig_out[tm] = sigma;
                const float diff = zbuf[tm] - febuf[tm];
                ll -= (diff * diff) / (2.f * sigma * sigma);
            }
            const float4* hv = reinterpret_cast<const float4*>(&hbuf[rp][0]);
            float a0 = 0.f, a1 = 0.f, a2 = 0.f, a3 = 0.f;
#pragma unroll
            for (int m = 0; m < 16; m += 4) {
                a0 = fma4(w[m],     hv[4 * (m + 0) + q], a0);
                a1 = fma4(w[m + 1], hv[4 * (m + 1) + q], a1);
                a2 = fma4(w[m + 2], hv[4 * (m + 2) + q], a2);
                a3 = fma4(w[m + 3], hv[4 * (m + 3) + q], a3);
            }
            const float4* xv = reinterpret_cast<const float4*>(&xbuf[tt][0]);
#pragma unroll
            for (int m = 0; m < 4; ++m) a0 = fma4(wx[m], xv[4 * m + q], a0);

            float dot = (a0 + a1) + (a2 + a3);
            dot += __shfl_xor(dot, 1);
            dot += __shfl_xor(dot, 2);
            const float h = fast_tanh(dot + badd);
            if (q == 0) hbuf[t & 1][j] = h;
            sv_prev = h * wlin_lds[j];
            __syncthreads();
        }
        __syncthreads();
    }
    {
        float sv = sv_prev;
        sv += __shfl_xor(sv, 4);
        sv += __shfl_xor(sv, 8);
        sv += __shfl_xor(sv, 16);
        sv += __shfl_xor(sv, 32);
        if (lane == 0) wsum[(T_CNT - 1) & 1][wv] = sv;
    }
    __syncthreads();
    if (tid == 0) {
        for (int tm = T_CNT - 2; tm < T_CNT; ++tm) {
            const float* wp = wsum[tm & 1];
            float sg = (((wp[0] + wp[1]) + (wp[2] + wp[3])) +
                        ((wp[4] + wp[5]) + (wp[6] + wp[7]))) +
                       (((wp[8] + wp[9]) + (wp[10] + wp[11])) +
                        ((wp[12] + wp[13]) + (wp[14] + wp[15]))) + blin;
            const float sigma = fabsf(sg);
            sig_out[tm] = sigma;
            const float diff = zbuf[tm] - febuf[tm];
            ll -= (diff * diff) / (2.f * sigma * sigma);
        }
        atomicAdd(out, ll);
    }
}

extern "C" void kernel_launch(void* const* d_in, const int* in_sizes, int n_in,
                              void* d_out, int out_size, void* d_ws, size_t ws_size,
                              hipStream_t stream) {
    (void)in_sizes; (void)n_in; (void)out_size;
    const float* input_data = (const float*)d_in[0];
    const float* hidden     = (const float*)d_in[1];
    const float* fe         = (const float*)d_in[2];
    const float* W_ih       = (const float*)d_in[3];
    const float* W_hh       = (const float*)d_in[4];
    const float* b_ih       = (const float*)d_in[5];
    const float* b_hh       = (const float*)d_in[6];
    const float* W_lin      = (const float*)d_in[7];
    const float* b_lin      = (const float*)d_in[8];
    float* out = (float*)d_out;

    hipMemsetAsync(d_out, 0, sizeof(float), stream);

    const size_t u_bytes   = (size_t)S_CNT * T_CNT * H_DIM * sizeof(float);
    const size_t pad_bytes = (size_t)H_DIM * sizeof(float);   // final prefetch overread

    if (ws_size >= u_bytes + pad_bytes) {
        float* U = (float*)d_ws;
        precompute_u2<<<dim3(S_CNT, 16), 128, 0, stream>>>(
            input_data, W_ih, b_ih, b_hh, U);
        rnn_main6<<<dim3(S_CNT), dim3(512), 0, stream>>>(hidden, W_hh, U);
        finalize_kernel<<<dim3(S_CNT, 4), 256, 0, stream>>>(
            input_data, fe, W_lin, b_lin, U, out);
    } else {
        rnn_fallback_kernel<<<dim3(S_CNT), dim3(1024), 0, stream>>>(
            input_data, hidden, fe, W_ih, W_hh, b_ih, b_hh, W_lin, b_lin, out);
    }
}

// Round 9
// 1865.876 us; speedup vs baseline: 1.2354x; 1.2354x over previous
//
#include <hip/hip_runtime.h>
#include <cmath>

#define S_CNT 50
#define T_CNT 2048
#define I_DIM 64
#define H_DIM 256
#define CHK   16          // timesteps per staging chunk
#define NCHK  (T_CNT / CHK)

typedef float vf2 __attribute__((ext_vector_type(2)));

__device__ __forceinline__ float fast_tanh(float x) {
    float e = __expf(2.0f * x);
    return 1.0f - __fdividef(2.0f, e + 1.0f);
}

__device__ __forceinline__ vf2 pkfma(vf2 a, vf2 b, vf2 c) {
#if __has_builtin(__builtin_elementwise_fma)
    return __builtin_elementwise_fma(a, b, c);
#else
    vf2 r; r.x = fmaf(a.x, b.x, c.x); r.y = fmaf(a.y, b.y, c.y); return r;
#endif
}

__device__ __forceinline__ float fma4(const float4 w, const float4 h, float a) {
    a = fmaf(w.x, h.x, a);
    a = fmaf(w.y, h.y, a);
    a = fmaf(w.z, h.z, a);
    a = fmaf(w.w, h.w, a);
    return a;
}

// x + DPP(x): VALU-pipe cross-lane add. CTRLs: 0xB1 quad xor1, 0x4E quad xor2,
// 0x141 row_half_mirror (xor7 within 16), 0x140 row_mirror (xor15 within 16).
template <int CTRL>
__device__ __forceinline__ float dpp_xadd(float x) {
    const int xi = __float_as_int(x);
    const int yi = __builtin_amdgcn_update_dpp(xi, xi, CTRL, 0xF, 0xF, false);
    return x + __int_as_float(yi);
}

// Workgroup barrier draining ONLY LDS (lgkmcnt). The in-loop code has zero
// VMEM, so vmcnt never needs draining inside the recurrence.
__device__ __forceinline__ void lgkm_barrier() {
    asm volatile("s_waitcnt lgkmcnt(0)\n\ts_barrier" ::: "memory");
}

// U[s][t][j] = b_ih[s][j] + b_hh[s][j] + W_ih[s][j]·x[s][t]  (r7 version)
__launch_bounds__(256, 4)
__global__ void precompute_u_kernel(const float* __restrict__ input_data,
                                    const float* __restrict__ W_ih,
                                    const float* __restrict__ b_ih,
                                    const float* __restrict__ b_hh,
                                    float* __restrict__ U)
{
    const int s  = blockIdx.x;
    const int tb = blockIdx.y;   // 16 t-slices of 128 steps
    const int j  = threadIdx.x;

    float4 w[16];
    const float4* wrow =
        reinterpret_cast<const float4*>(W_ih + ((size_t)s * H_DIM + j) * I_DIM);
#pragma unroll
    for (int k = 0; k < 16; ++k) w[k] = wrow[k];
    const float bsum = b_ih[s * H_DIM + j] + b_hh[s * H_DIM + j];

    __shared__ float xs[32][I_DIM];
    const float* inb = input_data + (size_t)s * T_CNT * 65;
    float* Ub = U + (size_t)s * T_CNT * H_DIM;

    for (int c = 0; c < 4; ++c) {
        const int t0 = tb * 128 + c * 32;
        __syncthreads();
        for (int idx = j; idx < 32 * I_DIM; idx += 256) {
            const int row = idx >> 6, col = idx & 63;
            xs[row][col] = inb[(size_t)(t0 + row) * 65 + 1 + col];
        }
        __syncthreads();
        for (int tt = 0; tt < 32; ++tt) {
            const float4* xv = reinterpret_cast<const float4*>(&xs[tt][0]);
            float a0 = bsum, a1 = 0.f, a2 = 0.f, a3 = 0.f;
#pragma unroll
            for (int k = 0; k < 16; k += 4) {
                a0 = fma4(w[k],     xv[k],     a0);
                a1 = fma4(w[k + 1], xv[k + 1], a1);
                a2 = fma4(w[k + 2], xv[k + 2], a2);
                a3 = fma4(w[k + 3], xv[k + 3], a3);
            }
            Ub[(size_t)(t0 + tt) * H_DIM + j] = (a0 + a1) + (a2 + a3);
        }
    }
}

// Main recurrence, 512 threads: tid = g*16 + p. Group g owns rows 8g..8g+7;
// lane p owns float4 col-chunks f = 16m+p (m=0..3). Reduce over 16 lanes is
// all-DPP (xor1 -> xor7 -> xor15 -> xor2; verified r8). ZERO VMEM in-loop:
// U staged per 16-step chunk through LDS (reg-prefetched one chunk ahead),
// h kept in an LDS ring hist[16][256] and burst-stored once per chunk into
// the consumed U slots (coalesced float4). One lgkm-only barrier per step.
__launch_bounds__(512, 2)
__global__ void rnn_main7(const float* __restrict__ hidden,
                          const float* __restrict__ W_hh,
                          float* __restrict__ U)     // consumed, then reused as H-out
{
    const int s   = blockIdx.x;
    const int tid = threadIdx.x;
    const int g   = tid >> 4;     // 0..31: rows 8g..8g+7
    const int p   = tid & 15;     // col slice

    const int s1 = ((p ^ (p >> 2)) & 1);
    const int s2 = ((p ^ (p >> 3)) & 1);
    const int s3 = ((p >> 3) & 1);
    const int jr = s1 | (s2 << 1) | (s3 << 2);
    const int jown = 8 * g + jr;
    const bool wrsel = ((p & 2) == 0);

    __shared__ __align__(16) float hist[CHK][H_DIM];        // 16 KB h ring
    __shared__ __align__(16) float ustage[2][CHK * H_DIM];  // 32 KB U staging

    if (tid < H_DIM) hist[CHK - 1][tid] = hidden[s * H_DIM + tid];

    // weights: 8 rows x 4 float4 chunks (f = 16m+p) as vf2 pairs = 128 VGPR
    vf2 w2[8][8];
#pragma unroll
    for (int r = 0; r < 8; ++r) {
        const float4* wrow = reinterpret_cast<const float4*>(
            W_hh + ((size_t)s * H_DIM + 8 * g + r) * H_DIM);
#pragma unroll
        for (int m = 0; m < 4; ++m) {
            const float4 wv = wrow[16 * m + p];
            w2[r][2 * m]     = vf2{wv.x, wv.y};
            w2[r][2 * m + 1] = vf2{wv.z, wv.w};
        }
    }

    float* Ub = U + (size_t)s * T_CNT * H_DIM;

    // prologue: chunk 0 into regs (2 float4 per thread)
    float4 ur0, ur1;
    {
        const float4* src = reinterpret_cast<const float4*>(Ub) + tid * 2;
        ur0 = src[0];
        ur1 = src[1];
    }

    for (int c = 0; c < NCHK; ++c) {
        float* ust = &ustage[c & 1][0];

        // (1) commit staged regs for chunk c (compiler inserts the vmcnt wait;
        //     loads were issued one full chunk ago -> no stall in steady state)
        {
            float4* dst = reinterpret_cast<float4*>(ust) + tid * 2;
            dst[0] = ur0;
            dst[1] = ur1;
        }
        // (2) issue prefetch of chunk c+1 (consumed at next boundary)
        if (c + 1 < NCHK) {
            const float4* src =
                reinterpret_cast<const float4*>(Ub + (size_t)(c + 1) * (CHK * H_DIM)) +
                tid * 2;
            ur0 = src[0];
            ur1 = src[1];
        }
        // (3) burst-store previous chunk's h into its (consumed) U slots
        if (c > 0) {
            const float4* hsrc =
                reinterpret_cast<const float4*>(&hist[0][0]) + tid * 2;
            float4* hdst =
                reinterpret_cast<float4*>(Ub + (size_t)(c - 1) * (CHK * H_DIM)) +
                tid * 2;
            const float4 h0 = hsrc[0], h1 = hsrc[1];
            hdst[0] = h0;
            hdst[1] = h1;
        }
        // drain LDS ops (ustage writes visible, hist burst-reads retired)
        lgkm_barrier();

#pragma unroll
        for (int tt = 0; tt < CHK; ++tt) {
            const float u = ust[tt * H_DIM + jown];            // ds_read_b32
            const float4* hv =
                reinterpret_cast<const float4*>(&hist[(tt + CHK - 1) & (CHK - 1)][0]);
            vf2 acc[8];
#pragma unroll
            for (int r = 0; r < 8; ++r) acc[r] = vf2{0.f, 0.f};
#pragma unroll
            for (int m = 0; m < 4; ++m) {
                const float4 h4 = hv[16 * m + p];              // ds_read_b128
                const vf2 hlo = vf2{h4.x, h4.y};
                const vf2 hhi = vf2{h4.z, h4.w};
#pragma unroll
                for (int r = 0; r < 8; ++r) {
                    acc[r] = pkfma(w2[r][2 * m],     hlo, acc[r]);
                    acc[r] = pkfma(w2[r][2 * m + 1], hhi, acc[r]);
                }
            }
            float d[8];
#pragma unroll
            for (int r = 0; r < 8; ++r) d[r] = acc[r].x + acc[r].y;
            // stage 1: xor1 (quad DPP), keep row-bit0 = s1
#pragma unroll
            for (int r = 0; r < 8; ++r) d[r] = dpp_xadd<0xB1>(d[r]);
            float e0 = s1 ? d[1] : d[0];
            float e1 = s1 ? d[3] : d[2];
            float e2 = s1 ? d[5] : d[4];
            float e3 = s1 ? d[7] : d[6];
            // stage 2: xor7 (row_half_mirror), keep row-bit1 = s2
            e0 = dpp_xadd<0x141>(e0);
            e1 = dpp_xadd<0x141>(e1);
            e2 = dpp_xadd<0x141>(e2);
            e3 = dpp_xadd<0x141>(e3);
            float f0 = s2 ? e1 : e0;
            float f1 = s2 ? e3 : e2;
            // stage 3: xor15 (row_mirror), keep row-bit2 = s3
            f0 = dpp_xadd<0x140>(f0);
            f1 = dpp_xadd<0x140>(f1);
            float v = s3 ? f1 : f0;
            // stage 4: xor2 (quad DPP), duplicate merge
            v = dpp_xadd<0x4E>(v);

            const float hval = fast_tanh(v + u);
            if (wrsel) hist[tt][jown] = hval;                  // ds_write_b32
            lgkm_barrier();
        }
    }

    // epilogue: store the final chunk's h
    {
        const float4* hsrc = reinterpret_cast<const float4*>(&hist[0][0]) + tid * 2;
        float4* hdst =
            reinterpret_cast<float4*>(Ub + (size_t)(NCHK - 1) * (CHK * H_DIM)) +
            tid * 2;
        hdst[0] = hsrc[0];
        hdst[1] = hsrc[1];
    }
}

// finalize: sigma[s][t] = |W_lin·h_t + b_lin|, log-lik reduction.
// H == U buffer (overwritten by rnn_main7 with h_t).
__launch_bounds__(256, 4)
__global__ void finalize_kernel(const float* __restrict__ input_data,
                                const float* __restrict__ fe,
                                const float* __restrict__ W_lin,
                                const float* __restrict__ b_lin,
                                const float* __restrict__ H,
                                float* __restrict__ out)
{
    const int s    = blockIdx.x;
    const int tb   = blockIdx.y;   // 4 slices of 512 timesteps
    const int tid  = threadIdx.x;
    const int wave = tid >> 6;
    const int lane = tid & 63;

    const float4 wl =
        reinterpret_cast<const float4*>(W_lin + s * H_DIM)[lane];
    const float blin = b_lin[s];
    const float* Hb  = H + (size_t)s * T_CNT * H_DIM;
    const float* inb = input_data + (size_t)s * T_CNT * 65;
    const float* feb = fe + (size_t)s * T_CNT;
    float* sig_out   = out + 1 + (size_t)s * T_CNT;

    float ll = 0.f;
    for (int i = 0; i < 128; ++i) {
        const int t = tb * 512 + 4 * i + wave;
        const float4 h4 =
            reinterpret_cast<const float4*>(Hb + (size_t)t * H_DIM)[lane];
        float d = fma4(wl, h4, 0.f);
#pragma unroll
        for (int m = 1; m <= 32; m <<= 1) d += __shfl_xor(d, m);
        const float sigma = fabsf(d + blin);
        if (lane == 0) {
            sig_out[t] = sigma;
            const float diff = inb[(size_t)t * 65] - feb[t];
            ll -= (diff * diff) / (2.f * sigma * sigma);
        }
    }
    __shared__ float red[4];
    if (lane == 0) red[wave] = ll;
    __syncthreads();
    if (tid == 0) atomicAdd(out, (red[0] + red[1]) + (red[2] + red[3]));
}

// ---------------- fallback (no workspace): round-3 style, self-contained ----
__launch_bounds__(1024, 4)
__global__ void rnn_fallback_kernel(const float* __restrict__ input_data,
                                    const float* __restrict__ hidden,
                                    const float* __restrict__ fe,
                                    const float* __restrict__ W_ih,
                                    const float* __restrict__ W_hh,
                                    const float* __restrict__ b_ih,
                                    const float* __restrict__ b_hh,
                                    const float* __restrict__ W_lin,
                                    const float* __restrict__ b_lin,
                                    float* __restrict__ out)
{
    const int s    = blockIdx.x;
    const int tid  = threadIdx.x;
    const int j    = tid >> 2;
    const int q    = tid & 3;
    const int lane = tid & 63;
    const int wv   = tid >> 6;

    __shared__ float hbuf[2][H_DIM];
    __shared__ float zbuf[T_CNT];
    __shared__ float febuf[T_CNT];
    __shared__ float wlin_lds[H_DIM];
    __shared__ float wsum[2][16];
    __shared__ float xbuf[64][I_DIM];

    const float* in_base = input_data + (size_t)s * T_CNT * 65;
    const float* fe_base = fe + (size_t)s * T_CNT;

    for (int t = tid; t < T_CNT; t += 1024) {
        zbuf[t]  = in_base[(size_t)t * 65];
        febuf[t] = fe_base[t];
    }
    if (tid < H_DIM) {
        hbuf[1][tid]  = hidden[s * H_DIM + tid];
        wlin_lds[tid] = W_lin[s * H_DIM + tid];
    }

    float4 w[16];
    {
        const float4* wrow =
            reinterpret_cast<const float4*>(W_hh + ((size_t)s * H_DIM + j) * H_DIM);
#pragma unroll
        for (int m = 0; m < 16; ++m) w[m] = wrow[4 * m + q];
    }
    float4 wx[4];
    {
        const float4* wxrow =
            reinterpret_cast<const float4*>(W_ih + ((size_t)s * H_DIM + j) * I_DIM);
#pragma unroll
        for (int m = 0; m < 4; ++m) wx[m] = wxrow[4 * m + q];
    }
    const float badd = b_ih[s * H_DIM + j] + b_hh[s * H_DIM + j];
    const float blin = b_lin[s];
    float* sig_out = out + 1 + (size_t)s * T_CNT;

    float ll = 0.f, sv_prev = 0.f;
    __syncthreads();

    for (int c = 0; c < T_CNT / 64; ++c) {
        for (int idx = tid; idx < 64 * I_DIM; idx += 1024) {
            const int row = idx >> 6, col = idx & 63;
            xbuf[row][col] = in_base[(size_t)(c * 64 + row) * 65 + 1 + col];
        }
        __syncthreads();
        for (int tt = 0; tt < 64; ++tt) {
            const int t  = c * 64 + tt;
            const int rp = (t + 1) & 1;
            {
                float sv = sv_prev;
                sv += __shfl_xor(sv, 4);
                sv += __shfl_xor(sv, 8);
                sv += __shfl_xor(sv, 16);
                sv += __shfl_xor(sv, 32);
                if (lane == 0) wsum[(t - 1) & 1][wv] = sv;
            }
            if (tid == 0 && t >= 2) {
                const int tm = t - 2;
                const float* wp = wsum[tm & 1];
                float sg = (((wp[0] + wp[1]) + (wp[2] + wp[3])) +
                            ((wp[4] + wp[5]) + (wp[6] + wp[7]))) +
                           (((wp[8] + wp[9]) + (wp[10] + wp[11])) +
                            ((wp[12] + wp[13]) + (wp[14] + wp[15]))) + blin;
                const float sigma = fabsf(sg);
                sig_out[tm] = sigma;
                const float diff = zbuf[tm] - febuf[tm];
                ll -= (diff * diff) / (2.f * sigma * sigma);
            }
            const float4* hv = reinterpret_cast<const float4*>(&hbuf[rp][0]);
            float a0 = 0.f, a1 = 0.f, a2 = 0.f, a3 = 0.f;
#pragma unroll
            for (int m = 0; m < 16; m += 4) {
                a0 = fma4(w[m],     hv[4 * (m + 0) + q], a0);
                a1 = fma4(w[m + 1], hv[4 * (m + 1) + q], a1);
                a2 = fma4(w[m + 2], hv[4 * (m + 2) + q], a2);
                a3 = fma4(w[m + 3], hv[4 * (m + 3) + q], a3);
            }
            const float4* xv = reinterpret_cast<const float4*>(&xbuf[tt][0]);
#pragma unroll
            for (int m = 0; m < 4; ++m) a0 = fma4(wx[m], xv[4 * m + q], a0);

            float dot = (a0 + a1) + (a2 + a3);
            dot += __shfl_xor(dot, 1);
            dot += __shfl_xor(dot, 2);
            const float h = fast_tanh(dot + badd);
            if (q == 0) hbuf[t & 1][j] = h;
            sv_prev = h * wlin_lds[j];
            __syncthreads();
        }
        __syncthreads();
    }
    {
        float sv = sv_prev;
        sv += __shfl_xor(sv, 4);
        sv += __shfl_xor(sv, 8);
        sv += __shfl_xor(sv, 16);
        sv += __shfl_xor(sv, 32);
        if (lane == 0) wsum[(T_CNT - 1) & 1][wv] = sv;
    }
    __syncthreads();
    if (tid == 0) {
        for (int tm = T_CNT - 2; tm < T_CNT; ++tm) {
            const float* wp = wsum[tm & 1];
            float sg = (((wp[0] + wp[1]) + (wp[2] + wp[3])) +
                        ((wp[4] + wp[5]) + (wp[6] + wp[7]))) +
                       (((wp[8] + wp[9]) + (wp[10] + wp[11])) +
                        ((wp[12] + wp[13]) + (wp[14] + wp[15]))) + blin;
            const float sigma = fabsf(sg);
            sig_out[tm] = sigma;
            const float diff = zbuf[tm] - febuf[tm];
            ll -= (diff * diff) / (2.f * sigma * sigma);
        }
        atomicAdd(out, ll);
    }
}

extern "C" void kernel_launch(void* const* d_in, const int* in_sizes, int n_in,
                              void* d_out, int out_size, void* d_ws, size_t ws_size,
                              hipStream_t stream) {
    (void)in_sizes; (void)n_in; (void)out_size;
    const float* input_data = (const float*)d_in[0];
    const float* hidden     = (const float*)d_in[1];
    const float* fe         = (const float*)d_in[2];
    const float* W_ih       = (const float*)d_in[3];
    const float* W_hh       = (const float*)d_in[4];
    const float* b_ih       = (const float*)d_in[5];
    const float* b_hh       = (const float*)d_in[6];
    const float* W_lin      = (const float*)d_in[7];
    const float* b_lin      = (const float*)d_in[8];
    float* out = (float*)d_out;

    hipMemsetAsync(d_out, 0, sizeof(float), stream);

    const size_t u_bytes = (size_t)S_CNT * T_CNT * H_DIM * sizeof(float);

    if (ws_size >= u_bytes) {
        float* U = (float*)d_ws;
        precompute_u_kernel<<<dim3(S_CNT, 16), 256, 0, stream>>>(
            input_data, W_ih, b_ih, b_hh, U);
        rnn_main7<<<dim3(S_CNT), dim3(512), 0, stream>>>(hidden, W_hh, U);
        finalize_kernel<<<dim3(S_CNT, 4), 256, 0, stream>>>(
            input_data, fe, W_lin, b_lin, U, out);
    } else {
        rnn_fallback_kernel<<<dim3(S_CNT), dim3(1024), 0, stream>>>(
            input_data, hidden, fe, W_ih, W_hh, b_ih, b_hh, W_lin, b_lin, out);
    }
}

// Round 10
// 1619.965 us; speedup vs baseline: 1.4229x; 1.1518x over previous
//
#include <hip/hip_runtime.h>
#include <cmath>

#define S_CNT 50
#define T_CNT 2048
#define I_DIM 64
#define H_DIM 256
#define CHK   8            // timesteps per u-register chunk
#define NCHK  (T_CNT / CHK)

typedef float vf2 __attribute__((ext_vector_type(2)));

__device__ __forceinline__ float fast_tanh(float x) {
    float e = __expf(2.0f * x);
    return 1.0f - __fdividef(2.0f, e + 1.0f);
}

__device__ __forceinline__ vf2 pkfma(vf2 a, vf2 b, vf2 c) {
#if __has_builtin(__builtin_elementwise_fma)
    return __builtin_elementwise_fma(a, b, c);
#else
    vf2 r; r.x = fmaf(a.x, b.x, c.x); r.y = fmaf(a.y, b.y, c.y); return r;
#endif
}

__device__ __forceinline__ float fma4(const float4 w, const float4 h, float a) {
    a = fmaf(w.x, h.x, a);
    a = fmaf(w.y, h.y, a);
    a = fmaf(w.z, h.z, a);
    a = fmaf(w.w, h.w, a);
    return a;
}

// x + quad_perm-DPP(x): VALU-pipe cross-lane add.
// CTRL: 0xB1 = xor1 ([1,0,3,2]), 0x4E = xor2 ([2,3,0,1]).
template <int CTRL>
__device__ __forceinline__ float dpp_xadd(float x) {
    const int xi = __float_as_int(x);
    const int yi = __builtin_amdgcn_update_dpp(xi, xi, CTRL, 0xF, 0xF, false);
    return x + __int_as_float(yi);
}

// x + swizzle_xor4(x): one DS op (BitMode: xor_mask=4 -> 0x101F).
__device__ __forceinline__ float swz_xadd4(float x) {
    const int yi = __builtin_amdgcn_ds_swizzle(__float_as_int(x), 0x101F);
    return x + __int_as_float(yi);
}

// Barrier that drains ONLY LDS (lgkmcnt), leaving global loads/stores in
// flight (vmcnt never drained in-loop). sched_barrier(0) pins ordering so
// the ds_write stays before the waitcnt and the next step's ds_read stays
// after the s_barrier (HK 8-phase pattern).
__device__ __forceinline__ void lds_barrier() {
    __builtin_amdgcn_sched_barrier(0);
    asm volatile("s_waitcnt lgkmcnt(0)");
    __builtin_amdgcn_s_barrier();
    __builtin_amdgcn_sched_barrier(0);
}

// U[s][t][j] = b_ih[s][j] + b_hh[s][j] + W_ih[s][j]·x[s][t]
// grid (S,64): one 32-step slice per block for max parallelism.
__launch_bounds__(256, 4)
__global__ void precompute_u_kernel(const float* __restrict__ input_data,
                                    const float* __restrict__ W_ih,
                                    const float* __restrict__ b_ih,
                                    const float* __restrict__ b_hh,
                                    float* __restrict__ U)
{
    const int s  = blockIdx.x;
    const int tb = blockIdx.y;   // 64 t-slices of 32 steps
    const int j  = threadIdx.x;

    float4 w[16];
    const float4* wrow =
        reinterpret_cast<const float4*>(W_ih + ((size_t)s * H_DIM + j) * I_DIM);
#pragma unroll
    for (int k = 0; k < 16; ++k) w[k] = wrow[k];
    const float bsum = b_ih[s * H_DIM + j] + b_hh[s * H_DIM + j];

    __shared__ float xs[32][I_DIM];
    const float* inb = input_data + (size_t)s * T_CNT * 65;
    float* Ub = U + (size_t)s * T_CNT * H_DIM;

    const int t0 = tb * 32;
    for (int idx = j; idx < 32 * I_DIM; idx += 256) {
        const int row = idx >> 6, col = idx & 63;
        xs[row][col] = inb[(size_t)(t0 + row) * 65 + 1 + col];
    }
    __syncthreads();
    for (int tt = 0; tt < 32; ++tt) {
        const float4* xv = reinterpret_cast<const float4*>(&xs[tt][0]);
        float a0 = bsum, a1 = 0.f, a2 = 0.f, a3 = 0.f;
#pragma unroll
        for (int k = 0; k < 16; k += 4) {
            a0 = fma4(w[k],     xv[k],     a0);
            a1 = fma4(w[k + 1], xv[k + 1], a1);
            a2 = fma4(w[k + 2], xv[k + 2], a2);
            a3 = fma4(w[k + 3], xv[k + 3], a3);
        }
        Ub[(size_t)(t0 + tt) * H_DIM + j] = (a0 + a1) + (a2 + a3);
    }
}

// Main recurrence, 512 threads: EXACT r7 geometry (best measured).
// tid = g*8 + p. Group g owns rows 4g..4g+3; lane p owns float4 col-chunks
// f = 8m+p (m=0..7). Reduce: xor1(DPP) -> sel -> xor2(DPP) -> sel ->
// xor4 (1 ds_swizzle); lane p owns row jown = 4g+(p&3), p<4 writes.
// NEW vs r7: u comes from REGISTERS (double-buffered 8-step chunks,
// loads issued one chunk ahead) and the per-step barrier drains only
// lgkmcnt, so the h-store + u-loads stay in flight across barriers.
__launch_bounds__(512, 2)
__global__ void rnn_main8(const float* __restrict__ hidden,
                          const float* __restrict__ W_hh,
                          float* __restrict__ U)   // consumed, then reused as H-out
{
    const int s    = blockIdx.x;
    const int tid  = threadIdx.x;
    const int g    = tid >> 3;    // 0..63: row group (rows 4g..4g+3)
    const int p    = tid & 7;     // col slice
    const int jown = 4 * g + (p & 3);

    __shared__ __align__(16) float hA[H_DIM];
    __shared__ __align__(16) float hB[H_DIM];

    if (tid < H_DIM) hA[tid] = hidden[s * H_DIM + tid];

    // weights: 4 rows x 8 chunks of float4 (f = 8m+p), as packed vf2 pairs
    vf2 w2[4][16];
#pragma unroll
    for (int r = 0; r < 4; ++r) {
        const float4* wrow = reinterpret_cast<const float4*>(
            W_hh + ((size_t)s * H_DIM + 4 * g + r) * H_DIM);
#pragma unroll
        for (int m = 0; m < 8; ++m) {
            const float4 wv = wrow[8 * m + p];
            w2[r][2 * m]     = vf2{wv.x, wv.y};
            w2[r][2 * m + 1] = vf2{wv.z, wv.w};
        }
    }

    float* Ub = U + (size_t)s * T_CNT * H_DIM;
    float* us = Ub + jown;                 // h store ptr (advances H_DIM/step)

    // prologue: chunk 0 of u into registers
    const float* u0 = Ub + jown;
    float cu0 = u0[0 * H_DIM], cu1 = u0[1 * H_DIM];
    float cu2 = u0[2 * H_DIM], cu3 = u0[3 * H_DIM];
    float cu4 = u0[4 * H_DIM], cu5 = u0[5 * H_DIM];
    float cu6 = u0[6 * H_DIM], cu7 = u0[7 * H_DIM];
    const float* up = Ub + jown + CHK * H_DIM;   // chunk 1

    const bool wsel = (p < 4);
    const bool sel1 = (p & 1);
    const bool sel2 = (p & 2);

    __syncthreads();

#define RNN_STEP(HRD, HWR, UVAL)                                              \
    {                                                                         \
        const float4* hv = reinterpret_cast<const float4*>(HRD);              \
        vf2 a0 = vf2{0.f, 0.f}, b0 = vf2{0.f, 0.f};                           \
        vf2 a1 = vf2{0.f, 0.f}, b1 = vf2{0.f, 0.f};                           \
        vf2 a2 = vf2{0.f, 0.f}, b2 = vf2{0.f, 0.f};                           \
        vf2 a3 = vf2{0.f, 0.f}, b3 = vf2{0.f, 0.f};                           \
        _Pragma("unroll")                                                     \
        for (int m = 0; m < 8; ++m) {                                         \
            const float4 h4 = hv[8 * m + p];                                  \
            const vf2 hlo = vf2{h4.x, h4.y};                                  \
            const vf2 hhi = vf2{h4.z, h4.w};                                  \
            a0 = pkfma(w2[0][2 * m], hlo, a0);                                \
            b0 = pkfma(w2[0][2 * m + 1], hhi, b0);                            \
            a1 = pkfma(w2[1][2 * m], hlo, a1);                                \
            b1 = pkfma(w2[1][2 * m + 1], hhi, b1);                            \
            a2 = pkfma(w2[2][2 * m], hlo, a2);                                \
            b2 = pkfma(w2[2][2 * m + 1], hhi, b2);                            \
            a3 = pkfma(w2[3][2 * m], hlo, a3);                                \
            b3 = pkfma(w2[3][2 * m + 1], hhi, b3);                            \
        }                                                                     \
        const vf2 s0v = a0 + b0, s1v = a1 + b1;                               \
        const vf2 s2v = a2 + b2, s3v = a3 + b3;                               \
        const float d0 = s0v.x + s0v.y, d1 = s1v.x + s1v.y;                   \
        const float d2 = s2v.x + s2v.y, d3 = s3v.x + s3v.y;                   \
        const float e0 = dpp_xadd<0xB1>(d0);                                  \
        const float e1 = dpp_xadd<0xB1>(d1);                                  \
        const float e2 = dpp_xadd<0xB1>(d2);                                  \
        const float e3 = dpp_xadd<0xB1>(d3);                                  \
        const float c0 = sel1 ? e1 : e0;                                      \
        const float c1 = sel1 ? e3 : e2;                                      \
        const float f0 = dpp_xadd<0x4E>(c0);                                  \
        const float f1 = dpp_xadd<0x4E>(c1);                                  \
        const float gg = sel2 ? f1 : f0;                                      \
        const float fr = swz_xadd4(gg);                                       \
        const float hval = fast_tanh(fr + (UVAL));                            \
        if (wsel) { (HWR)[jown] = hval; *us = hval; }                         \
        us += H_DIM;                                                          \
        lds_barrier();                                                        \
    }

    for (int c = 0; c < NCHK; ++c) {
        // issue next-chunk u loads (consumed >= 8 steps later; pinned above
        // the first step by sched_barrier(0) inside lds_barrier of step 1)
        const float nx0 = up[0 * H_DIM], nx1 = up[1 * H_DIM];
        const float nx2 = up[2 * H_DIM], nx3 = up[3 * H_DIM];
        const float nx4 = up[4 * H_DIM], nx5 = up[5 * H_DIM];
        const float nx6 = up[6 * H_DIM], nx7 = up[7 * H_DIM];

        RNN_STEP(hA, hB, cu0)
        RNN_STEP(hB, hA, cu1)
        RNN_STEP(hA, hB, cu2)
        RNN_STEP(hB, hA, cu3)
        RNN_STEP(hA, hB, cu4)
        RNN_STEP(hB, hA, cu5)
        RNN_STEP(hA, hB, cu6)
        RNN_STEP(hB, hA, cu7)

        cu0 = nx0; cu1 = nx1; cu2 = nx2; cu3 = nx3;
        cu4 = nx4; cu5 = nx5; cu6 = nx6; cu7 = nx7;
        if (c < NCHK - 2) up += CHK * H_DIM;   // stay on last chunk (no OOB)
    }
#undef RNN_STEP
}

// finalize: sigma[s][t] = |W_lin·h_t + b_lin|, log-lik reduction.
// H == U buffer (overwritten by rnn_main8 with h_t).
__launch_bounds__(256, 4)
__global__ void finalize_kernel(const float* __restrict__ input_data,
                                const float* __restrict__ fe,
                                const float* __restrict__ W_lin,
                                const float* __restrict__ b_lin,
                                const float* __restrict__ H,
                                float* __restrict__ out)
{
    const int s    = blockIdx.x;
    const int tb   = blockIdx.y;   // 4 slices of 512 timesteps
    const int tid  = threadIdx.x;
    const int wave = tid >> 6;
    const int lane = tid & 63;

    const float4 wl =
        reinterpret_cast<const float4*>(W_lin + s * H_DIM)[lane];
    const float blin = b_lin[s];
    const float* Hb  = H + (size_t)s * T_CNT * H_DIM;
    const float* inb = input_data + (size_t)s * T_CNT * 65;
    const float* feb = fe + (size_t)s * T_CNT;
    float* sig_out   = out + 1 + (size_t)s * T_CNT;

    float ll = 0.f;
    for (int i = 0; i < 128; ++i) {
        const int t = tb * 512 + 4 * i + wave;
        const float4 h4 =
            reinterpret_cast<const float4*>(Hb + (size_t)t * H_DIM)[lane];
        float d = fma4(wl, h4, 0.f);
#pragma unroll
        for (int m = 1; m <= 32; m <<= 1) d += __shfl_xor(d, m);
        const float sigma = fabsf(d + blin);
        if (lane == 0) {
            sig_out[t] = sigma;
            const float diff = inb[(size_t)t * 65] - feb[t];
            ll -= (diff * diff) / (2.f * sigma * sigma);
        }
    }
    __shared__ float red[4];
    if (lane == 0) red[wave] = ll;
    __syncthreads();
    if (tid == 0) atomicAdd(out, (red[0] + red[1]) + (red[2] + red[3]));
}

// ---------------- fallback (no workspace): round-3 style, self-contained ----
__launch_bounds__(1024, 4)
__global__ void rnn_fallback_kernel(const float* __restrict__ input_data,
                                    const float* __restrict__ hidden,
                                    const float* __restrict__ fe,
                                    const float* __restrict__ W_ih,
                                    const float* __restrict__ W_hh,
                                    const float* __restrict__ b_ih,
                                    const float* __restrict__ b_hh,
                                    const float* __restrict__ W_lin,
                                    const float* __restrict__ b_lin,
                                    float* __restrict__ out)
{
    const int s    = blockIdx.x;
    const int tid  = threadIdx.x;
    const int j    = tid >> 2;
    const int q    = tid & 3;
    const int lane = tid & 63;
    const int wv   = tid >> 6;

    __shared__ float hbuf[2][H_DIM];
    __shared__ float zbuf[T_CNT];
    __shared__ float febuf[T_CNT];
    __shared__ float wlin_lds[H_DIM];
    __shared__ float wsum[2][16];
    __shared__ float xbuf[64][I_DIM];

    const float* in_base = input_data + (size_t)s * T_CNT * 65;
    const float* fe_base = fe + (size_t)s * T_CNT;

    for (int t = tid; t < T_CNT; t += 1024) {
        zbuf[t]  = in_base[(size_t)t * 65];
        febuf[t] = fe_base[t];
    }
    if (tid < H_DIM) {
        hbuf[1][tid]  = hidden[s * H_DIM + tid];
        wlin_lds[tid] = W_lin[s * H_DIM + tid];
    }

    float4 w[16];
    {
        const float4* wrow =
            reinterpret_cast<const float4*>(W_hh + ((size_t)s * H_DIM + j) * H_DIM);
#pragma unroll
        for (int m = 0; m < 16; ++m) w[m] = wrow[4 * m + q];
    }
    float4 wx[4];
    {
        const float4* wxrow =
            reinterpret_cast<const float4*>(W_ih + ((size_t)s * H_DIM + j) * I_DIM);
#pragma unroll
        for (int m = 0; m < 4; ++m) wx[m] = wxrow[4 * m + q];
    }
    const float badd = b_ih[s * H_DIM + j] + b_hh[s * H_DIM + j];
    const float blin = b_lin[s];
    float* sig_out = out + 1 + (size_t)s * T_CNT;

    float ll = 0.f, sv_prev = 0.f;
    __syncthreads();

    for (int c = 0; c < T_CNT / 64; ++c) {
        for (int idx = tid; idx < 64 * I_DIM; idx += 1024) {
            const int row = idx >> 6, col = idx & 63;
            xbuf[row][col] = in_base[(size_t)(c * 64 + row) * 65 + 1 + col];
        }
        __syncthreads();
        for (int tt = 0; tt < 64; ++tt) {
            const int t  = c * 64 + tt;
            const int rp = (t + 1) & 1;
            {
                float sv = sv_prev;
                sv += __shfl_xor(sv, 4);
                sv += __shfl_xor(sv, 8);
                sv += __shfl_xor(sv, 16);
                sv += __shfl_xor(sv, 32);
                if (lane == 0) wsum[(t - 1) & 1][wv] = sv;
            }
            if (tid == 0 && t >= 2) {
                const int tm = t - 2;
                const float* wp = wsum[tm & 1];
                float sg = (((wp[0] + wp[1]) + (wp[2] + wp[3])) +
                            ((wp[4] + wp[5]) + (wp[6] + wp[7]))) +
                           (((wp[8] + wp[9]) + (wp[10] + wp[11])) +
                            ((wp[12] + wp[13]) + (wp[14] + wp[15]))) + blin;
                const float sigma = fabsf(sg);
                sig_out[tm] = sigma;
                const float diff = zbuf[tm] - febuf[tm];
                ll -= (diff * diff) / (2.f * sigma * sigma);
            }
            const float4* hv = reinterpret_cast<const float4*>(&hbuf[rp][0]);
            float a0 = 0.f, a1 = 0.f, a2 = 0.f, a3 = 0.f;
#pragma unroll
            for (int m = 0; m < 16; m += 4) {
                a0 = fma4(w[m],     hv[4 * (m + 0) + q], a0);
                a1 = fma4(w[m + 1], hv[4 * (m + 1) + q], a1);
                a2 = fma4(w[m + 2], hv[4 * (m + 2) + q], a2);
                a3 = fma4(w[m + 3], hv[4 * (m + 3) + q], a3);
            }
            const float4* xv = reinterpret_cast<const float4*>(&xbuf[tt][0]);
#pragma unroll
            for (int m = 0; m < 4; ++m) a0 = fma4(wx[m], xv[4 * m + q], a0);

            float dot = (a0 + a1) + (a2 + a3);
            dot += __shfl_xor(dot, 1);
            dot += __shfl_xor(dot, 2);
            const float h = fast_tanh(dot + badd);
            if (q == 0) hbuf[t & 1][j] = h;
            sv_prev = h * wlin_lds[j];
            __syncthreads();
        }
        __syncthreads();
    }
    {
        float sv = sv_prev;
        sv += __shfl_xor(sv, 4);
        sv += __shfl_xor(sv, 8);
        sv += __shfl_xor(sv, 16);
        sv += __shfl_xor(sv, 32);
        if (lane == 0) wsum[(T_CNT - 1) & 1][wv] = sv;
    }
    __syncthreads();
    if (tid == 0) {
        for (int tm = T_CNT - 2; tm < T_CNT; ++tm) {
            const float* wp = wsum[tm & 1];
            float sg = (((wp[0] + wp[1]) + (wp[2] + wp[3])) +
                        ((wp[4] + wp[5]) + (wp[6] + wp[7]))) +
                       (((wp[8] + wp[9]) + (wp[10] + wp[11])) +
                        ((wp[12] + wp[13]) + (wp[14] + wp[15]))) + blin;
            const float sigma = fabsf(sg);
            sig_out[tm] = sigma;
            const float diff = zbuf[tm] - febuf[tm];
            ll -= (diff * diff) / (2.f * sigma * sigma);
        }
        atomicAdd(out, ll);
    }
}

extern "C" void kernel_launch(void* const* d_in, const int* in_sizes, int n_in,
                              void* d_out, int out_size, void* d_ws, size_t ws_size,
                              hipStream_t stream) {
    (void)in_sizes; (void)n_in; (void)out_size;
    const float* input_data = (const float*)d_in[0];
    const float* hidden     = (const float*)d_in[1];
    const float* fe         = (const float*)d_in[2];
    const float* W_ih       = (const float*)d_in[3];
    const float* W_hh       = (const float*)d_in[4];
    const float* b_ih       = (const float*)d_in[5];
    const float* b_hh       = (const float*)d_in[6];
    const float* W_lin      = (const float*)d_in[7];
    const float* b_lin      = (const float*)d_in[8];
    float* out = (float*)d_out;

    hipMemsetAsync(d_out, 0, sizeof(float), stream);

    const size_t u_bytes = (size_t)S_CNT * T_CNT * H_DIM * sizeof(float);

    if (ws_size >= u_bytes) {
        float* U = (float*)d_ws;
        precompute_u_kernel<<<dim3(S_CNT, 64), 256, 0, stream>>>(
            input_data, W_ih, b_ih, b_hh, U);
        rnn_main8<<<dim3(S_CNT), dim3(512), 0, stream>>>(hidden, W_hh, U);
        finalize_kernel<<<dim3(S_CNT, 4), 256, 0, stream>>>(
            input_data, fe, W_lin, b_lin, U, out);
    } else {
        rnn_fallback_kernel<<<dim3(S_CNT), dim3(1024), 0, stream>>>(
            input_data, hidden, fe, W_ih, W_hh, b_ih, b_hh, W_lin, b_lin, out);
    }
}

// Round 12
// 1529.694 us; speedup vs baseline: 1.5069x; 1.0590x over previous
//
#include <hip/hip_runtime.h>
#include <cmath>

#define S_CNT 50
#define T_CNT 2048
#define I_DIM 64
#define H_DIM 256
#define CHK   8            // timesteps per u-register chunk
#define NCHK  (T_CNT / CHK)

typedef float vf2 __attribute__((ext_vector_type(2)));

__device__ __forceinline__ float fast_tanh(float x) {
    float e = __expf(2.0f * x);
    return 1.0f - __fdividef(2.0f, e + 1.0f);
}

__device__ __forceinline__ vf2 pkfma(vf2 a, vf2 b, vf2 c) {
#if __has_builtin(__builtin_elementwise_fma)
    return __builtin_elementwise_fma(a, b, c);
#else
    vf2 r; r.x = fmaf(a.x, b.x, c.x); r.y = fmaf(a.y, b.y, c.y); return r;
#endif
}

__device__ __forceinline__ float fma4(const float4 w, const float4 h, float a) {
    a = fmaf(w.x, h.x, a);
    a = fmaf(w.y, h.y, a);
    a = fmaf(w.z, h.z, a);
    a = fmaf(w.w, h.w, a);
    return a;
}

// x + DPP(x): VALU-pipe cross-lane add. CTRLs: 0xB1 quad xor1, 0x4E quad
// xor2, 0x141 row_half_mirror (lane ^ 7 within each 8-lane half-row).
template <int CTRL>
__device__ __forceinline__ float dpp_xadd(float x) {
    const int xi = __float_as_int(x);
    const int yi = __builtin_amdgcn_update_dpp(xi, xi, CTRL, 0xF, 0xF, false);
    return x + __int_as_float(yi);
}

// Barrier that drains ONLY LDS (lgkmcnt), leaving global loads/stores in
// flight (vmcnt never drained in-loop). Verified race-free r10.
__device__ __forceinline__ void lds_barrier() {
    __builtin_amdgcn_sched_barrier(0);
    asm volatile("s_waitcnt lgkmcnt(0)");
    __builtin_amdgcn_s_barrier();
    __builtin_amdgcn_sched_barrier(0);
}

// U[s][t][j] = b_ih[s][j] + b_hh[s][j] + W_ih[s][j]·x[s][t]
__launch_bounds__(256, 4)
__global__ void precompute_u_kernel(const float* __restrict__ input_data,
                                    const float* __restrict__ W_ih,
                                    const float* __restrict__ b_ih,
                                    const float* __restrict__ b_hh,
                                    float* __restrict__ U)
{
    const int s  = blockIdx.x;
    const int tb = blockIdx.y;   // 64 t-slices of 32 steps
    const int j  = threadIdx.x;

    float4 w[16];
    const float4* wrow =
        reinterpret_cast<const float4*>(W_ih + ((size_t)s * H_DIM + j) * I_DIM);
#pragma unroll
    for (int k = 0; k < 16; ++k) w[k] = wrow[k];
    const float bsum = b_ih[s * H_DIM + j] + b_hh[s * H_DIM + j];

    __shared__ float xs[32][I_DIM];
    const float* inb = input_data + (size_t)s * T_CNT * 65;
    float* Ub = U + (size_t)s * T_CNT * H_DIM;

    const int t0 = tb * 32;
    for (int idx = j; idx < 32 * I_DIM; idx += 256) {
        const int row = idx >> 6, col = idx & 63;
        xs[row][col] = inb[(size_t)(t0 + row) * 65 + 1 + col];
    }
    __syncthreads();
    for (int tt = 0; tt < 32; ++tt) {
        const float4* xv = reinterpret_cast<const float4*>(&xs[tt][0]);
        float a0 = bsum, a1 = 0.f, a2 = 0.f, a3 = 0.f;
#pragma unroll
        for (int k = 0; k < 16; k += 4) {
            a0 = fma4(w[k],     xv[k],     a0);
            a1 = fma4(w[k + 1], xv[k + 1], a1);
            a2 = fma4(w[k + 2], xv[k + 2], a2);
            a3 = fma4(w[k + 3], xv[k + 3], a3);
        }
        Ub[(size_t)(t0 + tt) * H_DIM + j] = (a0 + a1) + (a2 + a3);
    }
}

// Main recurrence, 512 threads, r10 structure with two changes:
// (1) waves_per_eu(1,2): allow up to 256+ arch VGPRs so the 128-float
//     weight array is NOT parked in AGPRs (kills per-use accvgpr copies).
// (2) reduce is ALL-DPP: xor1(0xB1) -> sel(s1=b0^b2) -> xor2(0x4E) ->
//     sel(s2=b0^b1) -> xor7(row_half_mirror 0x141). Lane p owns row
//     jr = s1 + 2*s2 (rows {0,3,2,1} for p=0..3); duplicates at p^7.
// u from registers (8-step double-buffered chunks); lgkm-only barrier.
__global__
__launch_bounds__(512)
__attribute__((amdgpu_waves_per_eu(1, 2)))
void rnn_main9(const float* __restrict__ hidden,
               const float* __restrict__ W_hh,
               float* __restrict__ U)   // consumed, then reused as H-out
{
    const int s    = blockIdx.x;
    const int tid  = threadIdx.x;
    const int g    = tid >> 3;    // 0..63: row group (rows 4g..4g+3)
    const int p    = tid & 7;     // col slice

    const int s1 = (p ^ (p >> 2)) & 1;
    const int s2 = (p ^ (p >> 1)) & 1;
    const int jr = s1 + 2 * s2;
    const int jown = 4 * g + jr;

    __shared__ __align__(16) float hA[H_DIM];
    __shared__ __align__(16) float hB[H_DIM];

    if (tid < H_DIM) hA[tid] = hidden[s * H_DIM + tid];

    // weights: 4 rows x 8 chunks of float4 (f = 8m+p), as packed vf2 pairs
    vf2 w2[4][16];
#pragma unroll
    for (int r = 0; r < 4; ++r) {
        const float4* wrow = reinterpret_cast<const float4*>(
            W_hh + ((size_t)s * H_DIM + 4 * g + r) * H_DIM);
#pragma unroll
        for (int m = 0; m < 8; ++m) {
            const float4 wv = wrow[8 * m + p];
            w2[r][2 * m]     = vf2{wv.x, wv.y};
            w2[r][2 * m + 1] = vf2{wv.z, wv.w};
        }
    }

    float* Ub = U + (size_t)s * T_CNT * H_DIM;
    float* us = Ub + jown;                 // h store ptr (advances H_DIM/step)

    // prologue: chunk 0 of u into registers
    const float* u0 = Ub + jown;
    float cu0 = u0[0 * H_DIM], cu1 = u0[1 * H_DIM];
    float cu2 = u0[2 * H_DIM], cu3 = u0[3 * H_DIM];
    float cu4 = u0[4 * H_DIM], cu5 = u0[5 * H_DIM];
    float cu6 = u0[6 * H_DIM], cu7 = u0[7 * H_DIM];
    const float* up = Ub + jown + CHK * H_DIM;   // chunk 1

    const bool wsel = (p < 4);
    const bool sel1 = (s1 != 0);
    const bool sel2 = (s2 != 0);

    __syncthreads();

#define RNN_STEP(HRD, HWR, UVAL)                                              \
    {                                                                         \
        const float4* hv = reinterpret_cast<const float4*>(HRD);              \
        vf2 a0 = vf2{0.f, 0.f}, b0 = vf2{0.f, 0.f};                           \
        vf2 a1 = vf2{0.f, 0.f}, b1 = vf2{0.f, 0.f};                           \
        vf2 a2 = vf2{0.f, 0.f}, b2 = vf2{0.f, 0.f};                           \
        vf2 a3 = vf2{0.f, 0.f}, b3 = vf2{0.f, 0.f};                           \
        _Pragma("unroll")                                                     \
        for (int m = 0; m < 8; ++m) {                                         \
            const float4 h4 = hv[8 * m + p];                                  \
            const vf2 hlo = vf2{h4.x, h4.y};                                  \
            const vf2 hhi = vf2{h4.z, h4.w};                                  \
            a0 = pkfma(w2[0][2 * m], hlo, a0);                                \
            b0 = pkfma(w2[0][2 * m + 1], hhi, b0);                            \
            a1 = pkfma(w2[1][2 * m], hlo, a1);                                \
            b1 = pkfma(w2[1][2 * m + 1], hhi, b1);                            \
            a2 = pkfma(w2[2][2 * m], hlo, a2);                                \
            b2 = pkfma(w2[2][2 * m + 1], hhi, b2);                            \
            a3 = pkfma(w2[3][2 * m], hlo, a3);                                \
            b3 = pkfma(w2[3][2 * m + 1], hhi, b3);                            \
        }                                                                     \
        const vf2 s0v = a0 + b0, s1v = a1 + b1;                               \
        const vf2 s2v = a2 + b2, s3v = a3 + b3;                               \
        const float d0 = s0v.x + s0v.y, d1 = s1v.x + s1v.y;                   \
        const float d2 = s2v.x + s2v.y, d3 = s3v.x + s3v.y;                   \
        /* xor1 (quad DPP) */                                                 \
        const float e0 = dpp_xadd<0xB1>(d0);                                  \
        const float e1 = dpp_xadd<0xB1>(d1);                                  \
        const float e2 = dpp_xadd<0xB1>(d2);                                  \
        const float e3 = dpp_xadd<0xB1>(d3);                                  \
        /* select by s1 = b0^b2 (invariant under ^2 and ^7) */                \
        const float c0 = sel1 ? e1 : e0;                                      \
        const float c1 = sel1 ? e3 : e2;                                      \
        /* xor2 (quad DPP) */                                                 \
        const float f0 = dpp_xadd<0x4E>(c0);                                  \
        const float f1 = dpp_xadd<0x4E>(c1);                                  \
        /* select by s2 = b0^b1 (invariant under ^7) */                       \
        const float gg = sel2 ? f1 : f0;                                      \
        /* xor7 via row_half_mirror DPP: full row sum, dup at p^7 */          \
        const float fr = dpp_xadd<0x141>(gg);                                 \
        const float hval = fast_tanh(fr + (UVAL));                            \
        if (wsel) { (HWR)[jown] = hval; *us = hval; }                         \
        us += H_DIM;                                                          \
        lds_barrier();                                                        \
    }

    for (int c = 0; c < NCHK; ++c) {
        // issue next-chunk u loads (consumed >= 8 steps later)
        const float nx0 = up[0 * H_DIM], nx1 = up[1 * H_DIM];
        const float nx2 = up[2 * H_DIM], nx3 = up[3 * H_DIM];
        const float nx4 = up[4 * H_DIM], nx5 = up[5 * H_DIM];
        const float nx6 = up[6 * H_DIM], nx7 = up[7 * H_DIM];

        RNN_STEP(hA, hB, cu0)
        RNN_STEP(hB, hA, cu1)
        RNN_STEP(hA, hB, cu2)
        RNN_STEP(hB, hA, cu3)
        RNN_STEP(hA, hB, cu4)
        RNN_STEP(hB, hA, cu5)
        RNN_STEP(hA, hB, cu6)
        RNN_STEP(hB, hA, cu7)

        cu0 = nx0; cu1 = nx1; cu2 = nx2; cu3 = nx3;
        cu4 = nx4; cu5 = nx5; cu6 = nx6; cu7 = nx7;
        if (c < NCHK - 2) up += CHK * H_DIM;   // stay on last chunk (no OOB)
    }
#undef RNN_STEP
}

// finalize: sigma[s][t] = |W_lin·h_t + b_lin|, log-lik reduction.
// H == U buffer (overwritten by rnn_main9 with h_t).
__launch_bounds__(256, 4)
__global__ void finalize_kernel(const float* __restrict__ input_data,
                                const float* __restrict__ fe,
                                const float* __restrict__ W_lin,
                                const float* __restrict__ b_lin,
                                const float* __restrict__ H,
                                float* __restrict__ out)
{
    const int s    = blockIdx.x;
    const int tb   = blockIdx.y;   // 4 slices of 512 timesteps
    const int tid  = threadIdx.x;
    const int wave = tid >> 6;
    const int lane = tid & 63;

    const float4 wl =
        reinterpret_cast<const float4*>(W_lin + s * H_DIM)[lane];
    const float blin = b_lin[s];
    const float* Hb  = H + (size_t)s * T_CNT * H_DIM;
    const float* inb = input_data + (size_t)s * T_CNT * 65;
    const float* feb = fe + (size_t)s * T_CNT;
    float* sig_out   = out + 1 + (size_t)s * T_CNT;

    float ll = 0.f;
    for (int i = 0; i < 128; ++i) {
        const int t = tb * 512 + 4 * i + wave;
        const float4 h4 =
            reinterpret_cast<const float4*>(Hb + (size_t)t * H_DIM)[lane];
        float d = fma4(wl, h4, 0.f);
#pragma unroll
        for (int m = 1; m <= 32; m <<= 1) d += __shfl_xor(d, m);
        const float sigma = fabsf(d + blin);
        if (lane == 0) {
            sig_out[t] = sigma;
            const float diff = inb[(size_t)t * 65] - feb[t];
            ll -= (diff * diff) / (2.f * sigma * sigma);
        }
    }
    __shared__ float red[4];
    if (lane == 0) red[wave] = ll;
    __syncthreads();
    if (tid == 0) atomicAdd(out, (red[0] + red[1]) + (red[2] + red[3]));
}

// ---------------- fallback (no workspace): round-3 style, self-contained ----
__launch_bounds__(1024, 4)
__global__ void rnn_fallback_kernel(const float* __restrict__ input_data,
                                    const float* __restrict__ hidden,
                                    const float* __restrict__ fe,
                                    const float* __restrict__ W_ih,
                                    const float* __restrict__ W_hh,
                                    const float* __restrict__ b_ih,
                                    const float* __restrict__ b_hh,
                                    const float* __restrict__ W_lin,
                                    const float* __restrict__ b_lin,
                                    float* __restrict__ out)
{
    const int s    = blockIdx.x;
    const int tid  = threadIdx.x;
    const int j    = tid >> 2;
    const int q    = tid & 3;
    const int lane = tid & 63;
    const int wv   = tid >> 6;

    __shared__ float hbuf[2][H_DIM];
    __shared__ float zbuf[T_CNT];
    __shared__ float febuf[T_CNT];
    __shared__ float wlin_lds[H_DIM];
    __shared__ float wsum[2][16];
    __shared__ float xbuf[64][I_DIM];

    const float* in_base = input_data + (size_t)s * T_CNT * 65;
    const float* fe_base = fe + (size_t)s * T_CNT;

    for (int t = tid; t < T_CNT; t += 1024) {
        zbuf[t]  = in_base[(size_t)t * 65];
        febuf[t] = fe_base[t];
    }
    if (tid < H_DIM) {
        hbuf[1][tid]  = hidden[s * H_DIM + tid];
        wlin_lds[tid] = W_lin[s * H_DIM + tid];
    }

    float4 w[16];
    {
        const float4* wrow =
            reinterpret_cast<const float4*>(W_hh + ((size_t)s * H_DIM + j) * H_DIM);
#pragma unroll
        for (int m = 0; m < 16; ++m) w[m] = wrow[4 * m + q];
    }
    float4 wx[4];
    {
        const float4* wxrow =
            reinterpret_cast<const float4*>(W_ih + ((size_t)s * H_DIM + j) * I_DIM);
#pragma unroll
        for (int m = 0; m < 4; ++m) wx[m] = wxrow[4 * m + q];
    }
    const float badd = b_ih[s * H_DIM + j] + b_hh[s * H_DIM + j];
    const float blin = b_lin[s];
    float* sig_out = out + 1 + (size_t)s * T_CNT;

    float ll = 0.f, sv_prev = 0.f;
    __syncthreads();

    for (int c = 0; c < T_CNT / 64; ++c) {
        for (int idx = tid; idx < 64 * I_DIM; idx += 1024) {
            const int row = idx >> 6, col = idx & 63;
            xbuf[row][col] = in_base[(size_t)(c * 64 + row) * 65 + 1 + col];
        }
        __syncthreads();
        for (int tt = 0; tt < 64; ++tt) {
            const int t  = c * 64 + tt;
            const int rp = (t + 1) & 1;
            {
                float sv = sv_prev;
                sv += __shfl_xor(sv, 4);
                sv += __shfl_xor(sv, 8);
                sv += __shfl_xor(sv, 16);
                sv += __shfl_xor(sv, 32);
                if (lane == 0) wsum[(t - 1) & 1][wv] = sv;
            }
            if (tid == 0 && t >= 2) {
                const int tm = t - 2;
                const float* wp = wsum[tm & 1];
                float sg = (((wp[0] + wp[1]) + (wp[2] + wp[3])) +
                            ((wp[4] + wp[5]) + (wp[6] + wp[7]))) +
                           (((wp[8] + wp[9]) + (wp[10] + wp[11])) +
                            ((wp[12] + wp[13]) + (wp[14] + wp[15]))) + blin;
                const float sigma = fabsf(sg);
                sig_out[tm] = sigma;
                const float diff = zbuf[tm] - febuf[tm];
                ll -= (diff * diff) / (2.f * sigma * sigma);
            }
            const float4* hv = reinterpret_cast<const float4*>(&hbuf[rp][0]);
            float a0 = 0.f, a1 = 0.f, a2 = 0.f, a3 = 0.f;
#pragma unroll
            for (int m = 0; m < 16; m += 4) {
                a0 = fma4(w[m],     hv[4 * (m + 0) + q], a0);
                a1 = fma4(w[m + 1], hv[4 * (m + 1) + q], a1);
                a2 = fma4(w[m + 2], hv[4 * (m + 2) + q], a2);
                a3 = fma4(w[m + 3], hv[4 * (m + 3) + q], a3);
            }
            const float4* xv = reinterpret_cast<const float4*>(&xbuf[tt][0]);
#pragma unroll
            for (int m = 0; m < 4; ++m) a0 = fma4(wx[m], xv[4 * m + q], a0);

            float dot = (a0 + a1) + (a2 + a3);
            dot += __shfl_xor(dot, 1);
            dot += __shfl_xor(dot, 2);
            const float h = fast_tanh(dot + badd);
            if (q == 0) hbuf[t & 1][j] = h;
            sv_prev = h * wlin_lds[j];
            __syncthreads();
        }
        __syncthreads();
    }
    {
        float sv = sv_prev;
        sv += __shfl_xor(sv, 4);
        sv += __shfl_xor(sv, 8);
        sv += __shfl_xor(sv, 16);
        sv += __shfl_xor(sv, 32);
        if (lane == 0) wsum[(T_CNT - 1) & 1][wv] = sv;
    }
    __syncthreads();
    if (tid == 0) {
        for (int tm = T_CNT - 2; tm < T_CNT; ++tm) {
            const float* wp = wsum[tm & 1];
            float sg = (((wp[0] + wp[1]) + (wp[2] + wp[3])) +
                        ((wp[4] + wp[5]) + (wp[6] + wp[7]))) +
                       (((wp[8] + wp[9]) + (wp[10] + wp[11])) +
                        ((wp[12] + wp[13]) + (wp[14] + wp[15]))) + blin;
            const float sigma = fabsf(sg);
            sig_out[tm] = sigma;
            const float diff = zbuf[tm] - febuf[tm];
            ll -= (diff * diff) / (2.f * sigma * sigma);
        }
        atomicAdd(out, ll);
    }
}

extern "C" void kernel_launch(void* const* d_in, const int* in_sizes, int n_in,
                              void* d_out, int out_size, void* d_ws, size_t ws_size,
                              hipStream_t stream) {
    (void)in_sizes; (void)n_in; (void)out_size;
    const float* input_data = (const float*)d_in[0];
    const float* hidden     = (const float*)d_in[1];
    const float* fe         = (const float*)d_in[2];
    const float* W_ih       = (const float*)d_in[3];
    const float* W_hh       = (const float*)d_in[4];
    const float* b_ih       = (const float*)d_in[5];
    const float* b_hh       = (const float*)d_in[6];
    const float* W_lin      = (const float*)d_in[7];
    const float* b_lin      = (const float*)d_in[8];
    float* out = (float*)d_out;

    hipMemsetAsync(d_out, 0, sizeof(float), stream);

    const size_t u_bytes = (size_t)S_CNT * T_CNT * H_DIM * sizeof(float);

    if (ws_size >= u_bytes) {
        float* U = (float*)d_ws;
        precompute_u_kernel<<<dim3(S_CNT, 64), 256, 0, stream>>>(
            input_data, W_ih, b_ih, b_hh, U);
        rnn_main9<<<dim3(S_CNT), dim3(512), 0, stream>>>(hidden, W_hh, U);
        finalize_kernel<<<dim3(S_CNT, 4), 256, 0, stream>>>(
            input_data, fe, W_lin, b_lin, U, out);
    } else {
        rnn_fallback_kernel<<<dim3(S_CNT), dim3(1024), 0, stream>>>(
            input_data, hidden, fe, W_ih, W_hh, b_ih, b_hh, W_lin, b_lin, out);
    }
}